// Round 1
// baseline (396.183 us; speedup 1.0000x reference)
//
#include <hip/hip_runtime.h>
#include <hip/hip_bf16.h>
#include <cstdint>
#include <cstddef>

// TripletLoss: inputs (8192,128) fp32, targets (8192,) int32, 64 classes.
// out[0] = loss, out[1..] = dist (8192x8192) row-major fp32.
// v2: (a) Xb pre-swizzled per row so MFMA-phase ds_read_b128 is conflict-free
// (global_load_lds needs linear dest -> swizzle lives in global layout);
// (b) output tile staged through LDS (reusing the 64KB A/B buffers) and
// written back as aligned, full-line, contiguous nontemporal dwordx4 runs
// (out+1 phase handled by a shfl_up shifted store); (c) per-row hard-pos/neg
// reduction fused into the row-contiguous readback (row is lane-resident).

#define NROWS 8192
#define DIMK  128
#define MARGIN 0.3f

typedef __bf16 bf16x8 __attribute__((ext_vector_type(8)));
typedef float  f32x4  __attribute__((ext_vector_type(4)));
typedef float  f32x2  __attribute__((ext_vector_type(2)));
typedef int    i32x4  __attribute__((ext_vector_type(4)));

__device__ __forceinline__ unsigned short f2bf(float f) {
    // round-to-nearest-even fp32 -> bf16
    unsigned u = __float_as_uint(f);
    u += 0x7fffu + ((u >> 16) & 1u);
    return (unsigned short)(u >> 16);
}

// prep: bf16-convert X into Xb with a per-row 16B-chunk XOR swizzle
// (byte ^= (row&7)<<4 within the 256B row), compute row sq-norms FROM THE
// ROUNDED VALUES, init ap/an. grid 2048 x 256 (one wave per row).
__global__ __launch_bounds__(256) void prep_kernel(
    const float* __restrict__ X, unsigned short* __restrict__ Xb,
    float* __restrict__ sq, int* __restrict__ ap, int* __restrict__ an)
{
    const int t = blockIdx.x * 256 + threadIdx.x;
    if (t < NROWS) { ap[t] = 0; an[t] = 0x7f800000; }  // 0.0f / +inf
    const int row  = t >> 6;
    const int lane = t & 63;
    const f32x2 v = *(const f32x2*)(X + (size_t)row * DIMK + lane * 2);
    const unsigned short b0 = f2bf(v[0]);
    const unsigned short b1 = f2bf(v[1]);
    const int swz = (row & 7) << 4;
    *(unsigned*)((char*)Xb + (size_t)row * 256 + ((lane * 4) ^ swz)) =
        (unsigned)b0 | ((unsigned)b1 << 16);
    const float f0 = __uint_as_float((unsigned)b0 << 16);
    const float f1 = __uint_as_float((unsigned)b1 << 16);
    float s = f0 * f0 + f1 * f1;
    #pragma unroll
    for (int off = 32; off; off >>= 1) s += __shfl_xor(s, off);
    if (lane == 0) sq[row] = s;
}

// dist kernel: 128x128 tile per block (grid 64x64), 256 threads = 4 waves,
// each wave a 64x64 subtile via 4x4 grid of 16x16x32 bf16 MFMA.
// Phase 1: global_load_lds stage (linear; rows pre-swizzled in global) +
//          conflict-free swizzled ds_read_b128 + MFMA.
// Phase 2: compute d, stage f32 tile into same LDS (chunk-XOR swizzle).
// Phase 3: row-contiguous readback -> aligned nt dwordx4 stores + fused
//          per-row max/min reduce (5 shfl steps per 32-lane row group).
__global__ __launch_bounds__(256, 2) void dist_kernel(
    const unsigned short* __restrict__ Xb, const float* __restrict__ sq,
    const int* __restrict__ tgt, float* __restrict__ dist,
    int* __restrict__ ap, int* __restrict__ an)
{
    __shared__ __align__(16) char lds[64 * 1024];  // A(32K)+B(32K) -> C(64K)

    const int t  = threadIdx.x;
    const int bm = blockIdx.x, bn = blockIdx.y;

    // ---- stage A and B tiles (each: 128 rows x 256B, contiguous) ----
    {
        const char* gA = (const char*)Xb + (size_t)bm * 32768;
        const char* gB = (const char*)Xb + (size_t)bn * 32768;
        #pragma unroll
        for (int i = 0; i < 8; i++) {
            const int off = i * 4096 + t * 16;
            __builtin_amdgcn_global_load_lds(
                (const __attribute__((address_space(1))) void*)(gA + off),
                (__attribute__((address_space(3))) void*)(lds + off),
                16, 0, 0);
            __builtin_amdgcn_global_load_lds(
                (const __attribute__((address_space(1))) void*)(gB + off),
                (__attribute__((address_space(3))) void*)(lds + 32768 + off),
                16, 0, 0);
        }
    }
    __syncthreads();

    const int lane = t & 63, wave = t >> 6;
    const int wm = (wave >> 1) * 64, wn = (wave & 1) * 64;
    const int l15 = lane & 15, quad = lane >> 4;

    f32x4 acc[4][4];
    #pragma unroll
    for (int mi = 0; mi < 4; mi++)
        #pragma unroll
        for (int ni = 0; ni < 4; ni++)
            acc[mi][ni] = (f32x4){0.f, 0.f, 0.f, 0.f};

    // ---- MFMA K loop: 4 k-steps of 32, swizzled conflict-free LDS reads ----
    #pragma unroll
    for (int ks = 0; ks < 4; ks++) {
        const int kb2 = ks * 64 + quad * 16;  // byte offset of 16B k-chunk
        bf16x8 a_frag[4], b_frag[4];
        #pragma unroll
        for (int mi = 0; mi < 4; mi++) {
            const int r = wm + mi * 16 + l15;
            a_frag[mi] = *(const bf16x8*)(lds + r * 256 + (kb2 ^ ((r & 7) << 4)));
        }
        #pragma unroll
        for (int ni = 0; ni < 4; ni++) {
            const int c = wn + ni * 16 + l15;
            b_frag[ni] = *(const bf16x8*)(lds + 32768 + c * 256 + (kb2 ^ ((c & 7) << 4)));
        }
        #pragma unroll
        for (int mi = 0; mi < 4; mi++)
            #pragma unroll
            for (int ni = 0; ni < 4; ni++)
                acc[mi][ni] = __builtin_amdgcn_mfma_f32_16x16x32_bf16(
                    a_frag[mi], b_frag[ni], acc[mi][ni], 0, 0, 0);
    }

    __syncthreads();  // all frag reads retired before C-tile overwrites A/B

    // ---- phase 2: sqd -> dist into LDS f32[128][128], 16B-chunk XOR swz ----
    // C/D layout: col = lane&15, row = quad*4 + reg (per frag).
    const int rbase = bm * 128;
    const int cbase = bn * 128;
    const float INF = __int_as_float(0x7f800000);

    float sqc[4]; int lc[4];
    #pragma unroll
    for (int ni = 0; ni < 4; ni++) {
        lc[ni]  = wn + ni * 16 + l15;          // local col 0..127
        sqc[ni] = sq[cbase + lc[ni]];
    }

    #pragma unroll
    for (int mi = 0; mi < 4; mi++) {
        const int rl0 = wm + mi * 16 + quad * 4;
        const f32x4 sqr = *(const f32x4*)(sq + rbase + rl0);
        #pragma unroll
        for (int reg = 0; reg < 4; reg++) {
            const int rl  = rl0 + reg;         // local row 0..127
            const int rg  = rbase + rl;
            const int swz = (rl & 7) << 4;
            #pragma unroll
            for (int ni = 0; ni < 4; ni++) {
                const float dot = acc[mi][ni][reg];
                float sqd = sqr[reg] + sqc[ni] - 2.0f * dot;
                float d = sqd > 0.0f ? sqrtf(sqd) : 0.0f;
                if (rg == cbase + lc[ni]) d = 0.0f;   // exact diagonal
                *(float*)(lds + rl * 512 + ((lc[ni] << 2) ^ swz)) = d;
            }
        }
    }
    __syncthreads();

    // ---- phase 3: row-contiguous readback, aligned nt stores, reduce ----
    // dist base is out+1 (4B phase off 16B): shift store window by one
    // element via shfl_up so every dwordx4 store is 16B-aligned.
    #pragma unroll 4
    for (int it = 0; it < 16; it++) {
        const int idx = it * 256 + t;
        const int r   = idx >> 5;              // local row, 32 lanes per row
        const int rc  = idx & 31;              // 16B chunk id within row
        const f32x4 d4 = *(const f32x4*)(lds + r * 512 + ((rc ^ (r & 7)) << 4));
        const int rg = rbase + r;
        float* drow = dist + (size_t)rg * NROWS + cbase;

        const float prev = __shfl_up(d4[3], 1);  // col 4rc-1 from neighbor
        if (rc == 0) {
            __builtin_nontemporal_store(d4[0], drow);
            const f32x2 v01 = {d4[1], d4[2]};
            __builtin_nontemporal_store(v01, (f32x2*)(drow + 1));
        } else {
            const f32x4 v = {prev, d4[0], d4[1], d4[2]};
            __builtin_nontemporal_store(v, (f32x4*)(drow + (rc << 2) - 1));
        }
        if (rc == 31)
            __builtin_nontemporal_store(d4[3], drow + 127);

        // fused per-row hard-pos / hard-neg over this block's 128 cols
        const int  trg = tgt[rg];
        const i32x4 tc = *(const i32x4*)(tgt + cbase + (rc << 2));
        float apv = -1.0f, anv = INF;
        #pragma unroll
        for (int j = 0; j < 4; j++) {
            const bool same = (trg == tc[j]);
            apv = fmaxf(apv, same ? d4[j] : -1.0f);
            anv = fminf(anv, same ? INF : d4[j]);
        }
        #pragma unroll
        for (int m = 1; m < 32; m <<= 1) {       // stays within 32-lane half
            apv = fmaxf(apv, __shfl_xor(apv, m));
            anv = fminf(anv, __shfl_xor(anv, m));
        }
        if ((t & 31) == 0) {
            atomicMax(ap + rg, __float_as_int(apv));
            atomicMin(an + rg, __float_as_int(anv));
        }
    }
}

__global__ __launch_bounds__(256) void loss_kernel(
    const int* __restrict__ ap, const int* __restrict__ an,
    float* __restrict__ out)
{
    __shared__ float red[4];
    float s = 0.0f;
    for (int i = threadIdx.x; i < NROWS; i += 256) {
        const float v = __int_as_float(ap[i]) - __int_as_float(an[i]) + MARGIN;
        s += v > 0.0f ? v : 0.0f;
    }
    #pragma unroll
    for (int off = 32; off; off >>= 1) s += __shfl_xor(s, off);
    if ((threadIdx.x & 63) == 0) red[threadIdx.x >> 6] = s;
    __syncthreads();
    if (threadIdx.x == 0)
        out[0] = (red[0] + red[1] + red[2] + red[3]) * (1.0f / NROWS);
}

extern "C" void kernel_launch(void* const* d_in, const int* in_sizes, int n_in,
                              void* d_out, int out_size, void* d_ws, size_t ws_size,
                              hipStream_t stream)
{
    const float* X   = (const float*)d_in[0];
    const int*   tgt = (const int*)d_in[1];
    float*       out = (float*)d_out;

    // ws layout: Xb bf16 8192x128 swizzled (2 MB) | sq (32 KB) | ap | an
    unsigned short* Xb = (unsigned short*)d_ws;
    float* sq = (float*)((char*)d_ws + (size_t)NROWS * DIMK * 2);
    int*   ap = (int*)(sq + NROWS);
    int*   an = ap + NROWS;

    prep_kernel<<<(NROWS * 64) / 256, 256, 0, stream>>>(X, Xb, sq, ap, an);

    dim3 grid(64, 64);
    dist_kernel<<<grid, 256, 0, stream>>>(Xb, sq, tgt, out + 1, ap, an);

    loss_kernel<<<1, 256, 0, stream>>>(ap, an, out);
}